// Round 6
// baseline (232.737 us; speedup 1.0000x reference)
//
#include <hip/hip_runtime.h>
#include <hip/hip_fp16.h>

#define BATCH  256
#define ICAPS  1152
#define OCAPS  10
#define OD     160
#define NW     12            // waves per block
#define BLOCK  (NW * 64)     // 768
#define RPW    (ICAPS / NW)  // 96 rows per wave
#define NG     (RPW / 16)    // 6 groups of 16 rows

// One block per batch element. One pass over x per routing iteration:
// lane = (r4 = row-in-group, dq = 4-wide column slice). Per o: load 4 halves,
// dot-partial, shfl over dq -> full dot in all 4 lanes; b-state in LDS;
// softmax in registers; same loaded halves feed the c*x accumulation.
__global__ __launch_bounds__(BLOCK, 3) void k_fused(const float* __restrict__ x,
                                                    __half* __restrict__ x16,
                                                    float* __restrict__ out) {
    __shared__ float b_lds[ICAPS * OCAPS];        // 46 KB routing logits
    __shared__ float part[NW][OD];                // per-wave partial col-sums
    __shared__ __align__(16) float v_lds[OD];

    const int b  = blockIdx.x;
    const int t  = threadIdx.x;
    const int w  = t >> 6;
    const int ln = t & 63;
    const int r4 = ln >> 2;      // 0..15 row within group
    const int dq = ln & 3;       // 0..3 column quad

    const size_t xb = (size_t)b * (ICAPS * OD);
    const float* xp = x + xb;
    __half*      hp = x16 + xb;

    const int wbase = w * RPW;
    float acc[OCAPS][4];

    for (int i = t; i < ICAPS * OCAPS; i += BLOCK) b_lds[i] = 0.f;

    // ---------- iter 0: fp32 read + fp16 write + col-sum (c = 0.1) ----------
    #pragma unroll
    for (int o = 0; o < OCAPS; ++o)
        #pragma unroll
        for (int j = 0; j < 4; ++j) acc[o][j] = 0.f;

    #pragma unroll
    for (int g = 0; g < NG; ++g) {
        const int row = wbase + g * 16 + r4;
        const float* rp = xp + row * OD + dq * 4;
        __half*      wp = hp + row * OD + dq * 4;
        #pragma unroll
        for (int o = 0; o < OCAPS; ++o) {
            const float4 v = *(const float4*)(rp + o * 16);
            __half2 h0 = __floats2half2_rn(v.x, v.y);
            __half2 h1 = __floats2half2_rn(v.z, v.w);
            uint2 u; u.x = *(unsigned*)&h0; u.y = *(unsigned*)&h1;
            *(uint2*)(wp + o * 16) = u;                 // 32B/row coalesced
            acc[o][0] += v.x; acc[o][1] += v.y; acc[o][2] += v.z; acc[o][3] += v.w;
        }
    }

    for (int it = 0; it <= 3; ++it) {
        if (it > 0) {
            // ---------- fused dot + b-update + softmax + weighted sum ----------
            #pragma unroll
            for (int o = 0; o < OCAPS; ++o)
                #pragma unroll
                for (int j = 0; j < 4; ++j) acc[o][j] = 0.f;

            #pragma unroll
            for (int g = 0; g < NG; ++g) {
                const int row = wbase + g * 16 + r4;
                const __half* rp = hp + row * OD + dq * 4;
                uint2 xr[OCAPS];
                float dots[OCAPS];
                #pragma unroll
                for (int o = 0; o < OCAPS; ++o) {
                    xr[o] = *(const uint2*)(rp + o * 16);
                    const float4 vv = *(const float4*)&v_lds[o * 16 + dq * 4];
                    const float2 f0 = __half22float2(*(const __half2*)&xr[o].x);
                    const float2 f1 = __half22float2(*(const __half2*)&xr[o].y);
                    float d = f0.x * vv.x + f0.y * vv.y + f1.x * vv.z + f1.y * vv.w;
                    d += __shfl_xor(d, 1, 64);
                    d += __shfl_xor(d, 2, 64);          // all 4 dq lanes: full dot
                    const float bv = b_lds[row * OCAPS + o] + d;   // broadcast read
                    dots[o] = bv;
                    if (dq == 0) b_lds[row * OCAPS + o] = bv;
                }
                float m = dots[0];
                #pragma unroll
                for (int o = 1; o < OCAPS; ++o) m = fmaxf(m, dots[o]);
                float e[OCAPS], sum = 0.f;
                #pragma unroll
                for (int o = 0; o < OCAPS; ++o) { e[o] = __expf(dots[o] - m); sum += e[o]; }
                const float inv = 1.f / sum;
                #pragma unroll
                for (int o = 0; o < OCAPS; ++o) {
                    const float c = e[o] * inv;
                    const float2 f0 = __half22float2(*(const __half2*)&xr[o].x);
                    const float2 f1 = __half22float2(*(const __half2*)&xr[o].y);
                    acc[o][0] += c * f0.x; acc[o][1] += c * f0.y;
                    acc[o][2] += c * f1.x; acc[o][3] += c * f1.y;
                }
            }
        }

        // ---------- butterfly over r4 lanes, cross-wave reduce, squash ----------
        #pragma unroll
        for (int o = 0; o < OCAPS; ++o)
            #pragma unroll
            for (int j = 0; j < 4; ++j) {
                float v = acc[o][j];
                v += __shfl_xor(v, 4, 64);
                v += __shfl_xor(v, 8, 64);
                v += __shfl_xor(v, 16, 64);
                v += __shfl_xor(v, 32, 64);
                if (r4 == 0) part[w][o * 16 + dq * 4 + j] = v;
            }
        __syncthreads();
        if (t < OD) {
            float s = 0.f;
            #pragma unroll
            for (int g = 0; g < NW; ++g) s += part[g][t];
            if (it == 0) s *= 0.1f;
            float sq = s * s;
            #pragma unroll
            for (int m = 1; m < 16; m <<= 1) sq += __shfl_xor(sq, m, 64);
            const float sc = sqrtf(sq) / (1.f + sq);
            if (it == 3) out[(size_t)b * OD + t] = s * sc;
            else         v_lds[t] = s * sc;
        }
        __syncthreads();
    }
}

extern "C" void kernel_launch(void* const* d_in, const int* in_sizes, int n_in,
                              void* d_out, int out_size, void* d_ws, size_t ws_size,
                              hipStream_t stream) {
    const float* x = (const float*)d_in[0];
    __half* x16 = (__half*)d_ws;             // 94.4 MB fp16 copy of x
    float* vout = (float*)d_out;
    k_fused<<<BATCH, BLOCK, 0, stream>>>(x, x16, vout);
}

// Round 8
// 130.082 us; speedup vs baseline: 1.7892x; 1.7892x over previous
//
#include <hip/hip_runtime.h>
#include <hip/hip_fp16.h>

#define BATCH  256
#define ICAPS  1152
#define OCAPS  10
#define OD     160            // OCAPS*16
#define BLOCK  960            // 15 waves
#define NPASS  12             // 11520 dot units / 960 threads
#define RGB    48             // row groups (phase B / iter0)
#define RPGB   24             // rows per group (1152/48)
#define VSTR   20             // padded v stride in floats (80B): 2-way banks max

typedef float v4f __attribute__((ext_vector_type(4)));   // native vec for NT loads

// One persistent block per batch element b. b-state in registers (breg[p]),
// v padded to stride-20 in LDS (kills the 5-way even/odd-o bank conflicts),
// fp32 x read nontemporally in pass 0 so L3 retains only the fp16 copy.
__global__ __launch_bounds__(BLOCK, 1) void k_routing(const float* __restrict__ x,
                                                      __half* __restrict__ x16,
                                                      float* __restrict__ out) {
    __shared__ float bc[ICAPS * OCAPS + 1152];   // per-iter logits, then c (in place)
    __shared__ float part[RGB][OD];              // partial col-sums
    __shared__ __align__(16) float v_pad[OCAPS * VSTR];

    const int b = blockIdx.x;
    const int t = threadIdx.x;
    const size_t xb = (size_t)b * (ICAPS * OD);

    const int c8  = t % 20;        // 8-col block 0..19
    const int rgb = t / 20;        // row group 0..47
    const int oB  = c8 >> 1;       // output capsule for phase B

    const float* xp  = x + xb;
    __half*      hpw = x16 + xb;
    const __half* hp = x16 + xb;

    float breg[NPASS];             // accumulated routing logits (b-state)
    #pragma unroll
    for (int p = 0; p < NPASS; ++p) breg[p] = 0.f;

    // ---------------- iter 0: NT fp32 read + fp16 write + col-sum (c = 0.1) ----------------
    {
        float a[8] = {0,0,0,0,0,0,0,0};
        #pragma unroll 4
        for (int k = 0; k < RPGB; ++k) {
            const int r = rgb * RPGB + k;
            const v4f v0 = __builtin_nontemporal_load((const v4f*)(xp + r * OD + c8 * 8));
            const v4f v1 = __builtin_nontemporal_load((const v4f*)(xp + r * OD + c8 * 8 + 4));
            __half2 h0 = __floats2half2_rn(v0.x, v0.y);
            __half2 h1 = __floats2half2_rn(v0.z, v0.w);
            __half2 h2 = __floats2half2_rn(v1.x, v1.y);
            __half2 h3 = __floats2half2_rn(v1.z, v1.w);
            uint4 u;
            u.x = *(unsigned*)&h0; u.y = *(unsigned*)&h1;
            u.z = *(unsigned*)&h2; u.w = *(unsigned*)&h3;
            *(uint4*)(hpw + r * OD + c8 * 8) = u;     // coalesced 16B/lane, cached
            a[0]+=v0.x; a[1]+=v0.y; a[2]+=v0.z; a[3]+=v0.w;
            a[4]+=v1.x; a[5]+=v1.y; a[6]+=v1.z; a[7]+=v1.w;
        }
        float* pp = &part[rgb][c8 * 8];
        #pragma unroll
        for (int j = 0; j < 8; ++j) pp[j] = a[j];
    }
    __syncthreads();
    if (t < OD) {     // reduce + 0.1 scale + squash -> v0
        float s = 0.f;
        #pragma unroll
        for (int g = 0; g < RGB; ++g) s += part[g][t];
        s *= 0.1f;
        float sq = s * s;
        #pragma unroll
        for (int m = 1; m < 16; m <<= 1) sq += __shfl_xor(sq, m, 64);
        v_pad[(t >> 4) * VSTR + (t & 15)] = s * sqrtf(sq) / (1.f + sq);
    }
    __syncthreads();

    // ---------------- iters 1..3 ----------------
    for (int it = 1; it <= 3; ++it) {
        // phase A: dot units (row,o); lanes consecutive -> 2KB contiguous reads/wave
        #pragma unroll
        for (int p = 0; p < NPASS; ++p) {
            const int u   = p * BLOCK + t;
            const int row = u / 10;
            const int o   = u - row * 10;
            const uint4 q0 = *(const uint4*)(hp + row * OD + o * 16);
            const uint4 q1 = *(const uint4*)(hp + row * OD + o * 16 + 8);
            const float4 w0 = *(const float4*)&v_pad[o * VSTR + 0];
            const float4 w1 = *(const float4*)&v_pad[o * VSTR + 4];
            const float4 w2 = *(const float4*)&v_pad[o * VSTR + 8];
            const float4 w3 = *(const float4*)&v_pad[o * VSTR + 12];
            float2 f0 = __half22float2(*(const __half2*)&q0.x);
            float2 f1 = __half22float2(*(const __half2*)&q0.y);
            float2 f2 = __half22float2(*(const __half2*)&q0.z);
            float2 f3 = __half22float2(*(const __half2*)&q0.w);
            const float d0 = f0.x*w0.x + f0.y*w0.y + f1.x*w0.z + f1.y*w0.w;
            const float d1 = f2.x*w1.x + f2.y*w1.y + f3.x*w1.z + f3.y*w1.w;
            f0 = __half22float2(*(const __half2*)&q1.x);
            f1 = __half22float2(*(const __half2*)&q1.y);
            f2 = __half22float2(*(const __half2*)&q1.z);
            f3 = __half22float2(*(const __half2*)&q1.w);
            const float d2 = f0.x*w2.x + f0.y*w2.y + f1.x*w2.z + f1.y*w2.w;
            const float d3 = f2.x*w3.x + f2.y*w3.y + f3.x*w3.z + f3.y*w3.w;
            breg[p] += (d0 + d1) + (d2 + d3);   // b accumulates across iterations
            bc[u] = breg[p];
        }
        __syncthreads();

        // per-row softmax over o, in place in bc
        for (int r = t; r < ICAPS; r += BLOCK) {
            float bv[OCAPS];
            #pragma unroll
            for (int o = 0; o < OCAPS; ++o) bv[o] = bc[r * 10 + o];
            float m = bv[0];
            #pragma unroll
            for (int o = 1; o < OCAPS; ++o) m = fmaxf(m, bv[o]);
            float e[OCAPS], sum = 0.f;
            #pragma unroll
            for (int o = 0; o < OCAPS; ++o) { e[o] = __expf(bv[o] - m); sum += e[o]; }
            const float inv = 1.f / sum;
            #pragma unroll
            for (int o = 0; o < OCAPS; ++o) bc[r * 10 + o] = e[o] * inv;
        }
        __syncthreads();

        // phase B: weighted col-sums; lanes consecutive -> coalesced 16B/lane
        {
            float a[8] = {0,0,0,0,0,0,0,0};
            #pragma unroll 4
            for (int k = 0; k < RPGB; ++k) {
                const int r = rgb * RPGB + k;
                const uint4 h = *(const uint4*)(hp + r * OD + c8 * 8);
                const float cc = bc[r * 10 + oB];
                const float2 g0 = __half22float2(*(const __half2*)&h.x);
                const float2 g1 = __half22float2(*(const __half2*)&h.y);
                const float2 g2 = __half22float2(*(const __half2*)&h.z);
                const float2 g3 = __half22float2(*(const __half2*)&h.w);
                a[0] += cc*g0.x; a[1] += cc*g0.y; a[2] += cc*g1.x; a[3] += cc*g1.y;
                a[4] += cc*g2.x; a[5] += cc*g2.y; a[6] += cc*g3.x; a[7] += cc*g3.y;
            }
            float* pp = &part[rgb][c8 * 8];
            #pragma unroll
            for (int j = 0; j < 8; ++j) pp[j] = a[j];
        }
        __syncthreads();

        if (t < OD) {   // reduce + squash
            float s = 0.f;
            #pragma unroll
            for (int g = 0; g < RGB; ++g) s += part[g][t];
            float sq = s * s;
            #pragma unroll
            for (int m = 1; m < 16; m <<= 1) sq += __shfl_xor(sq, m, 64);
            const float scale = sqrtf(sq) / (1.f + sq);
            if (it == 3) out[(size_t)b * OD + t] = s * scale;
            else         v_pad[(t >> 4) * VSTR + (t & 15)] = s * scale;
        }
        __syncthreads();
    }
}

extern "C" void kernel_launch(void* const* d_in, const int* in_sizes, int n_in,
                              void* d_out, int out_size, void* d_ws, size_t ws_size,
                              hipStream_t stream) {
    const float* x = (const float*)d_in[0];
    __half* x16 = (__half*)d_ws;             // 94.4 MB fp16 copy of x
    float* vout = (float*)d_out;
    k_routing<<<BATCH, BLOCK, 0, stream>>>(x, x16, vout);
}